// Round 9
// baseline (580.552 us; speedup 1.0000x reference)
//
#include <hip/hip_runtime.h>
#include <hip/hip_bf16.h>

#define T_STEPS 512
#define BATCH   256
#define FDIM    256
#define H1      128
#define H2      64
#define OUT_N   5
#define CAT     (H1 + H2)     // 192
#define LOG2E   1.4426950408889634f

typedef float v2f __attribute__((ext_vector_type(2)));
// Packed fp32 FMA: llvm.fma.v2f32 -> v_pk_fma_f32 on CDNA (2 MACs/instr).
#define PKFMA(a, b, c) __builtin_elementwise_fma((a), (b), (c))

#if __has_builtin(__builtin_amdgcn_exp2f)
#define EXP2F(x) __builtin_amdgcn_exp2f(x)
#else
#define EXP2F(x) exp2f(x)
#endif
#if __has_builtin(__builtin_amdgcn_rcpf)
#define RCPF(x) __builtin_amdgcn_rcpf(x)
#else
#define RCPF(x) (1.0f / (x))
#endif

// Workgroup barrier WITHOUT vmcnt drain: LDS ops ordered by lgkmcnt(0);
// global loads/stores (xp prefetch, h2_all store) stay in flight.
#define BAR() do {                                              \
    asm volatile("s_waitcnt lgkmcnt(0)" ::: "memory");          \
    __builtin_amdgcn_s_barrier();                               \
} while (0)

// v + v(permuted) via DPP. 0xB1 = quad_perm xor1, 0x4E = quad_perm xor2,
// 0x141 = row_half_mirror (acts as xor4 once quads are uniform).
template<int CTRL>
__device__ __forceinline__ float dpp_add(float v) {
    int s = __builtin_amdgcn_update_dpp(0, __float_as_int(v), CTRL, 0xF, 0xF, true);
    return v + __int_as_float(s);
}
__device__ __forceinline__ float sig_scaled(float a) {   // a = -log2e*x
    return RCPF(1.0f + EXP2F(a));
}
__device__ __forceinline__ float tanh_scaled(float a) {  // a = 2log2e*u
    return fmaf(-2.0f, RCPF(EXP2F(a) + 1.0f), 1.0f);
}

// ---------------------------------------------------------------------------
// Kernel 1: xp[t][g] = scale_g*(b_ih1[g] + badd_g + sum_f x[t,255,f]*w_ih1[g,f])
// ---------------------------------------------------------------------------
__global__ __launch_bounds__(256) void xp1_kernel(
    const float* __restrict__ x,
    const float* __restrict__ w_ih1,
    const float* __restrict__ b_ih1,
    const float* __restrict__ b_hh1,
    float* __restrict__ xp)
{
    __shared__ float xrow[FDIM];
    const int t = blockIdx.x;
    const float* xr = x + (size_t)t * BATCH * FDIM + (size_t)(BATCH - 1) * FDIM;
    if (threadIdx.x < FDIM / 4) {
        ((float4*)xrow)[threadIdx.x] = ((const float4*)xr)[threadIdx.x];
    }
    __syncthreads();
    const int q = threadIdx.x >> 2;
    const int s = threadIdx.x & 3;
    #pragma unroll
    for (int pass = 0; pass < 6; ++pass) {
        const int g = pass * 64 + q;
        const float* w = w_ih1 + (size_t)g * FDIM + (s << 2);
        float acc = 0.0f;
        #pragma unroll
        for (int c = 0; c < 16; ++c) {
            float4 wv = *(const float4*)(w + 16 * c);
            const float* xv = xrow + (s << 2) + 16 * c;
            acc = fmaf(wv.x, xv[0], acc);
            acc = fmaf(wv.y, xv[1], acc);
            acc = fmaf(wv.z, xv[2], acc);
            acc = fmaf(wv.w, xv[3], acc);
        }
        acc = dpp_add<0xB1>(acc);
        acc = dpp_add<0x4E>(acc);
        if (s == 0) {
            const bool isN = (g >= 2 * H1);
            const float badd  = isN ? 0.0f : b_hh1[g];
            const float scale = isN ? (2.0f * LOG2E) : (-LOG2E);
            xp[t * (3 * H1) + g] = scale * (acc + b_ih1[g] + badd);
        }
    }
}

// ---------------------------------------------------------------------------
// Kernel 2: single-CU, wave-specialized, 1024 thr = 16 waves — identical
// structure to round 8, with the matvec FMAs K-packed into v_pk_fma_f32
// (float2 accumulators folded once before the DPP reduce). FMA issue
// cycles/SIMD halve: 672 -> 336.
// ---------------------------------------------------------------------------
__global__ __launch_bounds__(1024) void gru_seq_kernel(
    const float* __restrict__ xp,
    const float* __restrict__ w_hh1, const float* __restrict__ b_hh1,
    const float* __restrict__ w_ih2, const float* __restrict__ b_ih2,
    const float* __restrict__ w_hh2, const float* __restrict__ b_hh2,
    float* __restrict__ h2_all)
{
    const int tid = threadIdx.x;
    __shared__ float cat0[CAT];   // [h1(128); h2(64)], written at even k
    __shared__ float cat1[CAT];   // written at odd k
    if (tid < CAT) { cat0[tid] = 0.0f; cat1[tid] = 0.0f; }

    const float sRZ = -LOG2E, sN = 2.0f * LOG2E;

    if (tid < 512) {
        // ============== LAYER-1 WAVES (G=2 row-pair) ==============
        const int g  = tid >> 3;          // row pair: rows 2g, 2g+1
        const int s  = tid & 7;           // K-slice: k = 4s + 32c, c<4
        const int hi = (tid >> 2) & 1;    // which row this lane's gates do
        const int r0 = 2 * g;

        v2f wr0[8], wz0[8], wn0[8], wr1[8], wz1[8], wn1[8];
        {
            const float* br0 = w_hh1 + (size_t)(         r0) * H1;
            const float* bz0 = w_hh1 + (size_t)(H1     + r0) * H1;
            const float* bn0 = w_hh1 + (size_t)(2 * H1 + r0) * H1;
            #pragma unroll
            for (int c = 0; c < 4; c++) {
                const int kk = (s << 2) + 32 * c;
                float4 v0 = *(const float4*)(br0 + kk);
                float4 v1 = *(const float4*)(bz0 + kk);
                float4 v2 = *(const float4*)(bn0 + kk);
                float4 v3 = *(const float4*)(br0 + H1 + kk);
                float4 v4 = *(const float4*)(bz0 + H1 + kk);
                float4 v5 = *(const float4*)(bn0 + H1 + kk);
                wr0[2*c+0] = (v2f){sRZ*v0.x, sRZ*v0.y}; wr0[2*c+1] = (v2f){sRZ*v0.z, sRZ*v0.w};
                wz0[2*c+0] = (v2f){sRZ*v1.x, sRZ*v1.y}; wz0[2*c+1] = (v2f){sRZ*v1.z, sRZ*v1.w};
                wn0[2*c+0] = (v2f){sN *v2.x, sN *v2.y}; wn0[2*c+1] = (v2f){sN *v2.z, sN *v2.w};
                wr1[2*c+0] = (v2f){sRZ*v3.x, sRZ*v3.y}; wr1[2*c+1] = (v2f){sRZ*v3.z, sRZ*v3.w};
                wz1[2*c+0] = (v2f){sRZ*v4.x, sRZ*v4.y}; wz1[2*c+1] = (v2f){sRZ*v4.z, sRZ*v4.w};
                wn1[2*c+0] = (v2f){sN *v5.x, sN *v5.y}; wn1[2*c+1] = (v2f){sN *v5.z, sN *v5.w};
            }
        }
        const float bn_a = sN * b_hh1[2 * H1 + r0];
        const float bn_b = sN * b_hh1[2 * H1 + r0 + 1];
        const float bh1n_s = hi ? bn_b : bn_a;

        float h1prev = 0.0f;
        float cxr, cxz, cxn;
        {
            float2 a2 = *(const float2*)(xp + r0);
            float2 b2 = *(const float2*)(xp + H1 + r0);
            float2 c2 = *(const float2*)(xp + 2 * H1 + r0);
            cxr = hi ? a2.y : a2.x; cxz = hi ? b2.y : b2.x; cxn = hi ? c2.y : c2.x;
        }
        BAR();   // [init]

        #define L1_BODY(RP, WP, K) do {                                                 \
            const float* hp = RP + (s << 2);                                            \
            v2f ar0v = (v2f){0.f,0.f}, az0v = ar0v, an0v = ar0v;                        \
            v2f ar1v = ar0v, az1v = ar0v, an1v = ar0v;                                  \
            _Pragma("unroll")                                                           \
            for (int cc = 0; cc < 4; cc++) {                                            \
                float4 h4 = *(const float4*)(hp + 32 * cc);                             \
                v2f hlo = (v2f){h4.x, h4.y}, hhi = (v2f){h4.z, h4.w};                   \
                ar0v = PKFMA(wr0[2*cc+0], hlo, ar0v); ar0v = PKFMA(wr0[2*cc+1], hhi, ar0v); \
                az0v = PKFMA(wz0[2*cc+0], hlo, az0v); az0v = PKFMA(wz0[2*cc+1], hhi, az0v); \
                an0v = PKFMA(wn0[2*cc+0], hlo, an0v); an0v = PKFMA(wn0[2*cc+1], hhi, an0v); \
                ar1v = PKFMA(wr1[2*cc+0], hlo, ar1v); ar1v = PKFMA(wr1[2*cc+1], hhi, ar1v); \
                az1v = PKFMA(wz1[2*cc+0], hlo, az1v); az1v = PKFMA(wz1[2*cc+1], hhi, az1v); \
                an1v = PKFMA(wn1[2*cc+0], hlo, an1v); an1v = PKFMA(wn1[2*cc+1], hhi, an1v); \
            }                                                                           \
            float2 a2, b2, c2;                                                          \
            {                                                                           \
                const int kn = ((K) < T_STEPS - 1) ? ((K) + 1) : (T_STEPS - 1);         \
                const float* nx = xp + (size_t)kn * (3 * H1);                           \
                a2 = *(const float2*)(nx + r0);                                         \
                b2 = *(const float2*)(nx + H1 + r0);                                    \
                c2 = *(const float2*)(nx + 2 * H1 + r0);                                \
            }                                                                           \
            float ar0 = ar0v.x + ar0v.y, az0 = az0v.x + az0v.y, an0 = an0v.x + an0v.y;  \
            float ar1 = ar1v.x + ar1v.y, az1 = az1v.x + az1v.y, an1 = an1v.x + an1v.y;  \
            ar0=dpp_add<0xB1>(ar0); ar0=dpp_add<0x4E>(ar0); ar0=dpp_add<0x141>(ar0);    \
            az0=dpp_add<0xB1>(az0); az0=dpp_add<0x4E>(az0); az0=dpp_add<0x141>(az0);    \
            an0=dpp_add<0xB1>(an0); an0=dpp_add<0x4E>(an0); an0=dpp_add<0x141>(an0);    \
            ar1=dpp_add<0xB1>(ar1); ar1=dpp_add<0x4E>(ar1); ar1=dpp_add<0x141>(ar1);    \
            az1=dpp_add<0xB1>(az1); az1=dpp_add<0x4E>(az1); az1=dpp_add<0x141>(az1);    \
            an1=dpp_add<0xB1>(an1); an1=dpp_add<0x4E>(an1); an1=dpp_add<0x141>(an1);    \
            const float ar = hi ? ar1 : ar0;                                            \
            const float az = hi ? az1 : az0;                                            \
            const float an = hi ? an1 : an0;                                            \
            const float r1g = sig_scaled(cxr + ar);                                     \
            const float z1g = sig_scaled(cxz + az);                                     \
            const float n1g = tanh_scaled(fmaf(r1g, an + bh1n_s, cxn));                 \
            const float h1new = fmaf(z1g, h1prev - n1g, n1g);                           \
            h1prev = h1new;                                                             \
            if ((tid & 3) == 0) WP[r0 + hi] = h1new;                                    \
            cxr = hi ? a2.y : a2.x; cxz = hi ? b2.y : b2.x; cxn = hi ? c2.y : c2.x;     \
        } while (0)

        #pragma unroll 1
        for (int i = 0; i < 256; i++) {       // slots k = 2i (even), 2i+1 (odd)
            L1_BODY(cat1, cat0, 2 * i);
            BAR();
            L1_BODY(cat0, cat1, 2 * i + 1);
            BAR();
        }
        BAR();                                 // slot 512 (L2's last)
        #undef L1_BODY
    } else {
        // ============== LAYER-2 WAVES (G=1) =======================
        const int t2 = tid - 512;
        const int j2 = t2 >> 3, s2 = t2 & 7;
        v2f w2r[12], w2z[12], w2n[12];
        {
            const float* ir  = w_ih2 + (size_t)(         j2) * H1;
            const float* iz  = w_ih2 + (size_t)(H2     + j2) * H1;
            const float* inn = w_ih2 + (size_t)(2 * H2 + j2) * H1;
            #pragma unroll
            for (int c = 0; c < 4; c++) {
                const int kk = (s2 << 2) + 32 * c;
                float4 vr = *(const float4*)(ir  + kk);
                float4 vz = *(const float4*)(iz  + kk);
                float4 vn = *(const float4*)(inn + kk);
                w2r[2*c+0] = (v2f){sRZ*vr.x, sRZ*vr.y}; w2r[2*c+1] = (v2f){sRZ*vr.z, sRZ*vr.w};
                w2z[2*c+0] = (v2f){sRZ*vz.x, sRZ*vz.y}; w2z[2*c+1] = (v2f){sRZ*vz.z, sRZ*vz.w};
                w2n[2*c+0] = (v2f){sN *vn.x, sN *vn.y}; w2n[2*c+1] = (v2f){sN *vn.z, sN *vn.w};
            }
            const float* hr = w_hh2 + (size_t)(         j2) * H2;
            const float* hz = w_hh2 + (size_t)(H2     + j2) * H2;
            const float* hn = w_hh2 + (size_t)(2 * H2 + j2) * H2;
            #pragma unroll
            for (int c = 0; c < 2; c++) {
                const int kk = (s2 << 2) + 32 * c;
                const int o = 2 * (c + 4);
                float4 vr = *(const float4*)(hr + kk);
                float4 vz = *(const float4*)(hz + kk);
                float4 vn = *(const float4*)(hn + kk);
                w2r[o+0] = (v2f){sRZ*vr.x, sRZ*vr.y}; w2r[o+1] = (v2f){sRZ*vr.z, sRZ*vr.w};
                w2z[o+0] = (v2f){sRZ*vz.x, sRZ*vz.y}; w2z[o+1] = (v2f){sRZ*vz.z, sRZ*vz.w};
                w2n[o+0] = (v2f){sN *vn.x, sN *vn.y}; w2n[o+1] = (v2f){sN *vn.z, sN *vn.w};
            }
        }
        const float b2r_s  = sRZ * (b_ih2[j2]      + b_hh2[j2]);
        const float b2z_s  = sRZ * (b_ih2[H2 + j2] + b_hh2[H2 + j2]);
        const float b2xn_s = sN  *  b_ih2[2 * H2 + j2];
        const float b2hn_s = sN  *  b_hh2[2 * H2 + j2];
        float h2prev = 0.0f;
        float* hout = h2_all + j2;
        BAR();   // [init]
        BAR();   // slot 0 (no L2 work)

        #define L2_BODY(RP, WP) do {                                                    \
            const float* gp = RP + (s2 << 2);                                           \
            v2f a2rv = (v2f){0.f,0.f}, a2zv = a2rv, axnv = a2rv, ahnv = a2rv;           \
            _Pragma("unroll")                                                           \
            for (int cc = 0; cc < 4; cc++) {                                            \
                float4 g4 = *(const float4*)(gp + 32 * cc);                             \
                v2f glo = (v2f){g4.x, g4.y}, ghi = (v2f){g4.z, g4.w};                   \
                a2rv = PKFMA(w2r[2*cc+0], glo, a2rv); a2rv = PKFMA(w2r[2*cc+1], ghi, a2rv); \
                a2zv = PKFMA(w2z[2*cc+0], glo, a2zv); a2zv = PKFMA(w2z[2*cc+1], ghi, a2zv); \
                axnv = PKFMA(w2n[2*cc+0], glo, axnv); axnv = PKFMA(w2n[2*cc+1], ghi, axnv); \
            }                                                                           \
            _Pragma("unroll")                                                           \
            for (int cc = 4; cc < 6; cc++) {                                            \
                float4 g4 = *(const float4*)(gp + 32 * cc);                             \
                v2f glo = (v2f){g4.x, g4.y}, ghi = (v2f){g4.z, g4.w};                   \
                a2rv = PKFMA(w2r[2*cc+0], glo, a2rv); a2rv = PKFMA(w2r[2*cc+1], ghi, a2rv); \
                a2zv = PKFMA(w2z[2*cc+0], glo, a2zv); a2zv = PKFMA(w2z[2*cc+1], ghi, a2zv); \
                ahnv = PKFMA(w2n[2*cc+0], glo, ahnv); ahnv = PKFMA(w2n[2*cc+1], ghi, ahnv); \
            }                                                                           \
            float a2r = a2rv.x + a2rv.y, a2z = a2zv.x + a2zv.y;                         \
            float axn = axnv.x + axnv.y, ahn = ahnv.x + ahnv.y;                         \
            a2r=dpp_add<0xB1>(a2r); a2r=dpp_add<0x4E>(a2r); a2r=dpp_add<0x141>(a2r);    \
            a2z=dpp_add<0xB1>(a2z); a2z=dpp_add<0x4E>(a2z); a2z=dpp_add<0x141>(a2z);    \
            axn=dpp_add<0xB1>(axn); axn=dpp_add<0x4E>(axn); axn=dpp_add<0x141>(axn);    \
            ahn=dpp_add<0xB1>(ahn); ahn=dpp_add<0x4E>(ahn); ahn=dpp_add<0x141>(ahn);    \
            const float r2 = sig_scaled(a2r + b2r_s);                                   \
            const float z2 = sig_scaled(a2z + b2z_s);                                   \
            const float n2 = tanh_scaled(fmaf(r2, ahn + b2hn_s, axn + b2xn_s));         \
            const float h2new = fmaf(z2, h2prev - n2, n2);                              \
            h2prev = h2new;                                                             \
            if (s2 == 0) { WP[H1 + j2] = h2new; *hout = h2new; }                        \
            hout += H2;                                                                 \
        } while (0)

        #pragma unroll 1
        for (int i = 0; i < 256; i++) {       // slots k = 2i+1, 2i+2
            L2_BODY(cat0, cat1);
            BAR();
            L2_BODY(cat1, cat0);
            BAR();
        }
        #undef L2_BODY
    }
}

// ---------------------------------------------------------------------------
// Kernel 3: out[t][o] = lin_b[o] + sum_j h2_all[t][j] * lin_w[o][j]
// ---------------------------------------------------------------------------
__global__ __launch_bounds__(256) void head_kernel(
    const float* __restrict__ h2_all,
    const float* __restrict__ lin_w,
    const float* __restrict__ lin_b,
    float* __restrict__ out)
{
    const int t = blockIdx.x * blockDim.x + threadIdx.x;
    if (t >= T_STEPS) return;
    const float* h = h2_all + t * H2;
    #pragma unroll
    for (int o = 0; o < OUT_N; o++) {
        float acc = lin_b[o];
        const float* w = lin_w + o * H2;
        #pragma unroll
        for (int j = 0; j < H2; j += 4) {
            float4 wv = *(const float4*)(w + j);
            float4 hv = *(const float4*)(h + j);
            acc = fmaf(wv.x, hv.x, acc);
            acc = fmaf(wv.y, hv.y, acc);
            acc = fmaf(wv.z, hv.z, acc);
            acc = fmaf(wv.w, hv.w, acc);
        }
        out[t * OUT_N + o] = acc;
    }
}

extern "C" void kernel_launch(void* const* d_in, const int* in_sizes, int n_in,
                              void* d_out, int out_size, void* d_ws, size_t ws_size,
                              hipStream_t stream) {
    const float* x     = (const float*)d_in[0];
    const float* w_ih1 = (const float*)d_in[1];
    const float* w_hh1 = (const float*)d_in[2];
    const float* b_ih1 = (const float*)d_in[3];
    const float* b_hh1 = (const float*)d_in[4];
    const float* w_ih2 = (const float*)d_in[5];
    const float* w_hh2 = (const float*)d_in[6];
    const float* b_ih2 = (const float*)d_in[7];
    const float* b_hh2 = (const float*)d_in[8];
    const float* lin_w = (const float*)d_in[9];
    const float* lin_b = (const float*)d_in[10];
    float* out = (float*)d_out;

    float* xp     = (float*)d_ws;                  // 512*384 floats (pre-scaled)
    float* h2_all = xp + T_STEPS * 3 * H1;         // 512*64 floats

    xp1_kernel<<<T_STEPS, 256, 0, stream>>>(x, w_ih1, b_ih1, b_hh1, xp);
    gru_seq_kernel<<<1, 1024, 0, stream>>>(xp, w_hh1, b_hh1,
                                           w_ih2, b_ih2, w_hh2, b_hh2, h2_all);
    head_kernel<<<(T_STEPS + 255) / 256, 256, 0, stream>>>(h2_all, lin_w, lin_b, out);
}